// Round 8
// baseline (245.093 us; speedup 1.0000x reference)
//
#include <hip/hip_runtime.h>

#define SS 2048
#define NH 16
#define NKV 4
#define HD 64

typedef __bf16 bf16;
typedef __bf16 bf16x8 __attribute__((ext_vector_type(8)));
typedef float f32x4 __attribute__((ext_vector_type(4)));

// softmax scale folded into Q at the QKV epilogue: (1/sqrt(64)) * log2(e)
#define SM_SCALE 0.18033688011f

__device__ __forceinline__ void gl_lds16(const bf16* g, bf16* l) {
    __builtin_amdgcn_global_load_lds((const __attribute__((address_space(1))) void*)g,
                                     (__attribute__((address_space(3))) void*)l, 16, 0, 0);
}

// ---------------- prep: convert x to bf16 + transpose/convert all weights ----------------
// blocks 0..255: Wq (16x16 64-tiles), 256..319: Wk, 320..383: Wv, 384..639: Wo,
// 640..1151: x fp32->bf16 (512 blocks x 256 thr x 8 float4 = 1,048,576 float4 = whole x).
__global__ __launch_bounds__(256) void prep_kernel(
    const float* __restrict__ x, const float* __restrict__ Wq, const float* __restrict__ Wk,
    const float* __restrict__ Wv, const float* __restrict__ Wo,
    bf16* __restrict__ xb, bf16* __restrict__ wqkv_t, bf16* __restrict__ wo_t)
{
    const int blk = blockIdx.x;
    const int tid = threadIdx.x;
    if (blk >= 640) {
        const float4* xv = (const float4*)x;
        const size_t base = (size_t)(blk - 640) * 2048 + tid;   // float4 units
        #pragma unroll
        for (int j = 0; j < 8; ++j) {
            const float4 v = xv[base + j * 256];
            bf16* o = xb + (base + j * 256) * 4;
            o[0] = (bf16)v.x; o[1] = (bf16)v.y; o[2] = (bf16)v.z; o[3] = (bf16)v.w;
        }
        return;
    }
    const float* W; bf16* Wt; int N, n0, k0;
    if (blk < 256)      { W = Wq; Wt = wqkv_t;                       N = 1024; n0 = (blk & 15) * 64;         k0 = (blk >> 4) * 64; }
    else if (blk < 320) { W = Wk; Wt = wqkv_t + (size_t)1024 * 1024; N = 256;  n0 = ((blk - 256) & 3) * 64;  k0 = ((blk - 256) >> 2) * 64; }
    else if (blk < 384) { W = Wv; Wt = wqkv_t + (size_t)1280 * 1024; N = 256;  n0 = ((blk - 320) & 3) * 64;  k0 = ((blk - 320) >> 2) * 64; }
    else                { W = Wo; Wt = wo_t;                         N = 1024; n0 = ((blk - 384) & 15) * 64; k0 = ((blk - 384) >> 4) * 64; }

    __shared__ float Ts[64][65];
    const int c = tid & 63, rr = tid >> 6;
    #pragma unroll
    for (int i = 0; i < 16; ++i) {
        const int kk = i * 4 + rr;
        Ts[kk][c] = W[(size_t)(k0 + kk) * N + n0 + c];
    }
    __syncthreads();
    #pragma unroll
    for (int i = 0; i < 16; ++i) {
        const int nn = i * 4 + rr;
        Wt[(size_t)(n0 + nn) * 1024 + k0 + c] = (bf16)Ts[c][nn];
    }
}

// ---------------- bf16 MFMA GEMM, 256 threads (4 waves), 128x64 tile, BK=64 ----------------
// A(M,K) rm bf16, Bt(N,K) rm bf16. Wave w owns rows w*32..w*32+31, all 64 cols.
// Chunk-XOR swizzled LDS (physical chunk p of row r holds logical chunk p^(r&7)).
// EPI=0: C fp32 plain. EPI=2: fused RoPE + QKV split epilogue (N=1536), Q pre-scaled by SM_SCALE.
template<int EPI>
__global__ __launch_bounds__(256) void gemm_bt_kernel(
    const bf16* __restrict__ A, const bf16* __restrict__ Bt, float* __restrict__ C,
    const float* __restrict__ cosp, const float* __restrict__ sinp,
    bf16* __restrict__ qo, bf16* __restrict__ ko, bf16* __restrict__ vto,
    int M, int N, int K)
{
    __shared__ bf16 As[128 * 64];   // 16 KB
    __shared__ bf16 Bs[64 * 64];    //  8 KB
    const int m0 = blockIdx.x * 128, n0 = blockIdx.y * 64;
    const int tid = threadIdx.x;
    const int w = tid >> 6, lane = tid & 63, g = lane >> 4, li = lane & 15;

    f32x4 acc[2][4];
    const f32x4 z = {0.f, 0.f, 0.f, 0.f};
    #pragma unroll
    for (int i = 0; i < 2; ++i)
        #pragma unroll
        for (int j = 0; j < 4; ++j) acc[i][j] = z;

    // staging: each gl_lds sweep = 256 thr x 16B = 32 rows x 64 elems.
    // thread t: row-in-call = t>>3, fetches logical chunk (t&7)^(row&7) at physical slot t&7.
    const int srow = tid >> 3;
    const int schunk = ((tid & 7) ^ (srow & 7)) * 8;
    const bf16* pA0 = A + (size_t)(m0 + srow) * K + schunk;
    const bf16* pA1 = A + (size_t)(m0 + 32 + srow) * K + schunk;
    const bf16* pA2 = A + (size_t)(m0 + 64 + srow) * K + schunk;
    const bf16* pA3 = A + (size_t)(m0 + 96 + srow) * K + schunk;
    const bf16* pB0 = Bt + (size_t)(n0 + srow) * K + schunk;
    const bf16* pB1 = Bt + (size_t)(n0 + 32 + srow) * K + schunk;
    bf16* lA0 = As + (size_t)w * 512;           // wave-uniform dests
    bf16* lA1 = As + 2048 + (size_t)w * 512;
    bf16* lA2 = As + 4096 + (size_t)w * 512;
    bf16* lA3 = As + 6144 + (size_t)w * 512;
    bf16* lB0 = Bs + (size_t)w * 512;
    bf16* lB1 = Bs + 2048 + (size_t)w * 512;

    for (int kk = 0; kk < K; kk += 64) {
        __syncthreads();
        gl_lds16(pA0 + kk, lA0);
        gl_lds16(pA1 + kk, lA1);
        gl_lds16(pA2 + kk, lA2);
        gl_lds16(pA3 + kk, lA3);
        gl_lds16(pB0 + kk, lB0);
        gl_lds16(pB1 + kk, lB1);
        __syncthreads();
        #pragma unroll
        for (int t = 0; t < 2; ++t) {
            const int phys = ((t * 4 + g) ^ (li & 7)) * 8;
            bf16x8 af[2], bfr[4];
            #pragma unroll
            for (int mi = 0; mi < 2; ++mi) af[mi] = *(const bf16x8*)&As[(w * 32 + mi * 16 + li) * 64 + phys];
            #pragma unroll
            for (int ni = 0; ni < 4; ++ni) bfr[ni] = *(const bf16x8*)&Bs[(ni * 16 + li) * 64 + phys];
            #pragma unroll
            for (int mi = 0; mi < 2; ++mi)
                #pragma unroll
                for (int ni = 0; ni < 4; ++ni)
                    acc[mi][ni] = __builtin_amdgcn_mfma_f32_16x16x32_bf16(af[mi], bfr[ni], acc[mi][ni], 0, 0, 0);
        }
    }

    const int row0 = m0 + w * 32;
    if (EPI == 0) {
        #pragma unroll
        for (int mi = 0; mi < 2; ++mi)
            #pragma unroll
            for (int ni = 0; ni < 4; ++ni)
                #pragma unroll
                for (int r = 0; r < 4; ++r)
                    C[(size_t)(row0 + mi * 16 + g * 4 + r) * N + n0 + ni * 16 + li] = acc[mi][ni][r];
    } else {
        // fused RoPE + split. cols: [0,1024) q (pre-scaled), [1024,1280) k, [1280,1536) v.
        // rotate_half partner of col is col^32 == acc[mi][ni^2][r] (same wave, in-register).
        #pragma unroll
        for (int ni = 0; ni < 4; ++ni) {
            const int col = n0 + ni * 16 + li;
            const int d = col & 63;
            #pragma unroll
            for (int mi = 0; mi < 2; ++mi) {
                #pragma unroll
                for (int r = 0; r < 4; ++r) {
                    const int row = row0 + mi * 16 + g * 4 + r;
                    const int bb = row >> 11, s = row & 2047;
                    float val = acc[mi][ni][r];
                    if (col < 1280) {
                        const float pairv = acc[mi][ni ^ 2][r];
                        const float rot = (d < 32) ? -pairv : pairv;
                        val = val * cosp[s * 64 + d] + rot * sinp[s * 64 + d];
                    }
                    if (col < 1024) {
                        const int hh = col >> 6;
                        qo[(((size_t)bb * NH + hh) * SS + s) * HD + d] = (bf16)(val * SM_SCALE);
                    } else if (col < 1280) {
                        const int kh = (col - 1024) >> 6;
                        ko[(((size_t)bb * NKV + kh) * SS + s) * HD + d] = (bf16)val;
                    } else {
                        const int kh = (col - 1280) >> 6;
                        vto[(((size_t)bb * NKV + kh) * HD + d) * SS + s] = (bf16)val;  // V^T: [d][s]
                    }
                }
            }
        }
    }
}

// ---------------- Flash attention v5: BARRIER-FREE ----------------
// 512 blocks x 512 threads. Waves 0-3 process qt=31-p, waves 4-7 process qt=p
// (each wave owns a 16-row Q slice). K and V^T fragments load DIRECTLY from
// global (b128, L1/L2-served) -> no staging LDS, no __syncthreads anywhere.
// P round-trips per-wave LDS (C-layout -> A-layout), same-wave, no barrier.
#define FP 72
__global__ __launch_bounds__(512) void flash_kernel(const bf16* __restrict__ q, const bf16* __restrict__ k,
                                                    const bf16* __restrict__ vt, bf16* __restrict__ o)
{
    __shared__ bf16 Ps[8][16][FP];   // per-wave P, column-XOR-swizzled by g

    const int blk = blockIdx.x;
    const int p = blk & 15;
    const int h = (blk >> 4) & 15;
    const int b = blk >> 8;
    const int kvh = h >> 2;
    const int tid = threadIdx.x;
    const int w = tid >> 6, lane = tid & 63, g = lane >> 4, li = lane & 15;
    const int wg = w & 3;                        // 16-row slice within the 64-row Q tile
    const int qt = (w < 4) ? (31 - p) : p;       // balanced pair: per SIMD one long + one short wave

    const bf16* qh = q + ((size_t)b * NH + h) * SS * HD;
    const bf16* kh = k + ((size_t)b * NKV + kvh) * SS * HD;
    const bf16* vh = vt + ((size_t)b * NKV + kvh) * (size_t)HD * SS;

    bf16x8 ones;
    #pragma unroll
    for (int j = 0; j < 8; ++j) ones[j] = (bf16)1.0f;
    const f32x4 z = {0.f, 0.f, 0.f, 0.f};

    // Q fragments (A-layout: row=li, k=g*8+j); Q pre-scaled by SM_SCALE.
    const bf16* qrow = qh + (size_t)(qt * 64 + wg * 16 + li) * HD;
    bf16x8 qf[2];
    qf[0] = *(const bf16x8*)(qrow + g * 8);
    qf[1] = *(const bf16x8*)(qrow + 32 + g * 8);

    f32x4 o_acc[4], l_acc;
    #pragma unroll
    for (int nt = 0; nt < 4; ++nt) o_acc[nt] = z;
    l_acc = z;

    for (int kt = 0; kt <= qt; ++kt) {
        // S = Q @ K^T : K fragments direct from global (B-layout: n=key=li, k=g*8+j)
        f32x4 s_acc[4];
        #pragma unroll
        for (int nt = 0; nt < 4; ++nt) s_acc[nt] = z;
        #pragma unroll
        for (int t = 0; t < 2; ++t)
            #pragma unroll
            for (int nt = 0; nt < 4; ++nt) {
                const bf16x8 kf = *(const bf16x8*)(kh + (size_t)(kt * 64 + nt * 16 + li) * HD + t * 32 + g * 8);
                s_acc[nt] = __builtin_amdgcn_mfma_f32_16x16x32_bf16(qf[t], kf, s_acc[nt], 0, 0, 0);
            }

        // exp2 + P -> per-wave LDS (bf16), column swizzled by g. Diag masked separately.
        if (kt == qt) {
            const int qr0 = qt * 64 + wg * 16 + g * 4;
            #pragma unroll
            for (int nt = 0; nt < 4; ++nt) {
                const int key = kt * 64 + nt * 16 + li;
                #pragma unroll
                for (int r = 0; r < 4; ++r) {
                    float sv = s_acc[nt][r];
                    if (key > qr0 + r) sv = -1e30f;
                    Ps[w][g * 4 + r][(nt * 16 + li) ^ (g * 16)] = (bf16)exp2f(sv);
                }
            }
        } else {
            #pragma unroll
            for (int nt = 0; nt < 4; ++nt)
                #pragma unroll
                for (int r = 0; r < 4; ++r)
                    Ps[w][g * 4 + r][(nt * 16 + li) ^ (g * 16)] = (bf16)exp2f(s_acc[nt][r]);
        }

        // O += P @ V ; l += P @ 1. V^T fragments direct from global (n=d=li, k=key=g*8+j).
        #pragma unroll
        for (int t = 0; t < 2; ++t) {
            const bf16x8 pf = *(const bf16x8*)&Ps[w][li][(t * 32 + g * 8) ^ ((li >> 2) * 16)];
            l_acc = __builtin_amdgcn_mfma_f32_16x16x32_bf16(pf, ones, l_acc, 0, 0, 0);
            #pragma unroll
            for (int nt = 0; nt < 4; ++nt) {
                const bf16x8 vf = *(const bf16x8*)(vh + (size_t)(nt * 16 + li) * SS + kt * 64 + t * 32 + g * 8);
                o_acc[nt] = __builtin_amdgcn_mfma_f32_16x16x32_bf16(pf, vf, o_acc[nt], 0, 0, 0);
            }
        }
    }

    // epilogue: O / l -> (b, s, h, d) bf16
    #pragma unroll
    for (int r = 0; r < 4; ++r) {
        const float inv = 1.f / l_acc[r];
        const int s = qt * 64 + wg * 16 + g * 4 + r;
        bf16* orow = o + (((size_t)b * SS + s) * NH + h) * HD;
        #pragma unroll
        for (int nt = 0; nt < 4; ++nt) orow[nt * 16 + li] = (bf16)(o_acc[nt][r] * inv);
    }
}

extern "C" void kernel_launch(void* const* d_in, const int* in_sizes, int n_in,
                              void* d_out, int out_size, void* d_ws, size_t ws_size,
                              hipStream_t stream) {
    const float* x     = (const float*)d_in[0];
    const float* cos_t = (const float*)d_in[1];
    const float* sin_t = (const float*)d_in[2];
    const float* Wq    = (const float*)d_in[3];
    const float* Wk    = (const float*)d_in[4];
    const float* Wv    = (const float*)d_in[5];
    const float* Wo    = (const float*)d_in[6];
    float* out = (float*)d_out;

    char* wsb = (char*)d_ws;
    bf16* x_b    = (bf16*)(wsb);                 //  8,388,608 B (aliased as o_b after QKV GEMM)
    bf16* wqkv_t = (bf16*)(wsb + 8388608);       //  3,145,728 B (1536 x 1024)
    bf16* wo_t   = (bf16*)(wsb + 11534336);      //  2,097,152 B (1024 x 1024)
    bf16* q_b    = (bf16*)(wsb + 13631488);      //  8,388,608 B
    bf16* k_b    = (bf16*)(wsb + 22020096);      //  2,097,152 B
    bf16* vt_b   = (bf16*)(wsb + 24117248);      //  2,097,152 B -> total 26,214,400 B
    bf16* o_b    = x_b;

    prep_kernel<<<1152, 256, 0, stream>>>(x, Wq, Wk, Wv, Wo, x_b, wqkv_t, wo_t);

    // QKV GEMM with fused RoPE + split (writes q_b pre-scaled, k_b, vt_b directly)
    gemm_bt_kernel<2><<<dim3(32, 24), 256, 0, stream>>>(x_b, wqkv_t, nullptr, cos_t, sin_t,
                                                        q_b, k_b, vt_b, 4096, 1536, 1024);
    flash_kernel<<<512, 512, 0, stream>>>(q_b, k_b, vt_b, o_b);
    gemm_bt_kernel<0><<<dim3(32, 16), 256, 0, stream>>>(o_b, wo_t, out, nullptr, nullptr,
                                                        nullptr, nullptr, nullptr, 4096, 1024, 1024);
}

// Round 9
// 182.088 us; speedup vs baseline: 1.3460x; 1.3460x over previous
//
#include <hip/hip_runtime.h>

#define SS 2048
#define NH 16
#define NKV 4
#define HD 64

typedef __bf16 bf16;
typedef __bf16 bf16x8 __attribute__((ext_vector_type(8)));
typedef float f32x4 __attribute__((ext_vector_type(4)));

// softmax scale folded into Q at the QKV epilogue: (1/sqrt(64)) * log2(e)
#define SM_SCALE 0.18033688011f

__device__ __forceinline__ void gl_lds16(const bf16* g, bf16* l) {
    __builtin_amdgcn_global_load_lds((const __attribute__((address_space(1))) void*)g,
                                     (__attribute__((address_space(3))) void*)l, 16, 0, 0);
}

// ---------------- prep: convert x to bf16 + transpose/convert all weights ----------------
// blocks 0..255: Wq (16x16 64-tiles), 256..319: Wk, 320..383: Wv, 384..639: Wo,
// 640..1151: x fp32->bf16 (512 blocks x 256 thr x 8 float4 = 1,048,576 float4 = whole x).
__global__ __launch_bounds__(256) void prep_kernel(
    const float* __restrict__ x, const float* __restrict__ Wq, const float* __restrict__ Wk,
    const float* __restrict__ Wv, const float* __restrict__ Wo,
    bf16* __restrict__ xb, bf16* __restrict__ wqkv_t, bf16* __restrict__ wo_t)
{
    const int blk = blockIdx.x;
    const int tid = threadIdx.x;
    if (blk >= 640) {
        const float4* xv = (const float4*)x;
        const size_t base = (size_t)(blk - 640) * 2048 + tid;   // float4 units
        #pragma unroll
        for (int j = 0; j < 8; ++j) {
            const float4 v = xv[base + j * 256];
            bf16* o = xb + (base + j * 256) * 4;
            o[0] = (bf16)v.x; o[1] = (bf16)v.y; o[2] = (bf16)v.z; o[3] = (bf16)v.w;
        }
        return;
    }
    const float* W; bf16* Wt; int N, n0, k0;
    if (blk < 256)      { W = Wq; Wt = wqkv_t;                       N = 1024; n0 = (blk & 15) * 64;         k0 = (blk >> 4) * 64; }
    else if (blk < 320) { W = Wk; Wt = wqkv_t + (size_t)1024 * 1024; N = 256;  n0 = ((blk - 256) & 3) * 64;  k0 = ((blk - 256) >> 2) * 64; }
    else if (blk < 384) { W = Wv; Wt = wqkv_t + (size_t)1280 * 1024; N = 256;  n0 = ((blk - 320) & 3) * 64;  k0 = ((blk - 320) >> 2) * 64; }
    else                { W = Wo; Wt = wo_t;                         N = 1024; n0 = ((blk - 384) & 15) * 64; k0 = ((blk - 384) >> 4) * 64; }

    __shared__ float Ts[64][65];
    const int c = tid & 63, rr = tid >> 6;
    #pragma unroll
    for (int i = 0; i < 16; ++i) {
        const int kk = i * 4 + rr;
        Ts[kk][c] = W[(size_t)(k0 + kk) * N + n0 + c];
    }
    __syncthreads();
    #pragma unroll
    for (int i = 0; i < 16; ++i) {
        const int nn = i * 4 + rr;
        Wt[(size_t)(n0 + nn) * 1024 + k0 + c] = (bf16)Ts[c][nn];
    }
}

// ---------------- bf16 MFMA GEMM, 256 threads (4 waves), 64x128 tile, BK=32 ----------------
// A(M,K) rm bf16, Bt(N,K) rm bf16. Wave grid 2(row)x2(col): wave tile 32x64.
// m97-proven unpadded LDS layout (rows of 32 elems = 64 B).
// EPI=0: C fp32 plain. EPI=2: fused RoPE + QKV split epilogue (N=1536), Q pre-scaled by SM_SCALE.
template<int EPI>
__global__ __launch_bounds__(256) void gemm_bt_kernel(
    const bf16* __restrict__ A, const bf16* __restrict__ Bt, float* __restrict__ C,
    const float* __restrict__ cosp, const float* __restrict__ sinp,
    bf16* __restrict__ qo, bf16* __restrict__ ko, bf16* __restrict__ vto,
    int M, int N, int K)
{
    __shared__ bf16 As[64 * 32];    // 4 KB
    __shared__ bf16 Bs[128 * 32];   // 8 KB
    const int m0 = blockIdx.x * 64, n0 = blockIdx.y * 128;
    const int tid = threadIdx.x;
    const int w = tid >> 6, lane = tid & 63, g = lane >> 4, li = lane & 15;
    const int wm = w >> 1, wn = w & 1;      // wave tile: rows wm*32+mi*16 (mi<2), cols wn*64+ni*16 (ni<4)

    f32x4 acc[2][4];
    const f32x4 z = {0.f, 0.f, 0.f, 0.f};
    #pragma unroll
    for (int i = 0; i < 2; ++i)
        #pragma unroll
        for (int j = 0; j < 4; ++j) acc[i][j] = z;

    // staging: sweep = 256 thr x 16 B = 64 rows x 32 elems. thread t -> row t>>2, chunk t&3.
    // wave-uniform dests: wave w covers rows 16w..16w+15 -> base + w*512 elems.
    const int srow = tid >> 2, schunk = (tid & 3) * 8;
    const bf16* pA  = A  + (size_t)(m0 + srow) * K + schunk;
    const bf16* pB0 = Bt + (size_t)(n0 + srow) * K + schunk;
    const bf16* pB1 = Bt + (size_t)(n0 + 64 + srow) * K + schunk;
    bf16* lA  = As + (size_t)w * 512;
    bf16* lB0 = Bs + (size_t)w * 512;
    bf16* lB1 = Bs + 2048 + (size_t)w * 512;

    for (int kk = 0; kk < K; kk += 32) {
        __syncthreads();
        gl_lds16(pA + kk, lA);
        gl_lds16(pB0 + kk, lB0);
        gl_lds16(pB1 + kk, lB1);
        __syncthreads();
        bf16x8 af[2], bfr[4];
        #pragma unroll
        for (int mi = 0; mi < 2; ++mi) af[mi] = *(const bf16x8*)&As[(wm * 32 + mi * 16 + li) * 32 + g * 8];
        #pragma unroll
        for (int ni = 0; ni < 4; ++ni) bfr[ni] = *(const bf16x8*)&Bs[(wn * 64 + ni * 16 + li) * 32 + g * 8];
        #pragma unroll
        for (int mi = 0; mi < 2; ++mi)
            #pragma unroll
            for (int ni = 0; ni < 4; ++ni)
                acc[mi][ni] = __builtin_amdgcn_mfma_f32_16x16x32_bf16(af[mi], bfr[ni], acc[mi][ni], 0, 0, 0);
    }

    const int row0 = m0 + wm * 32, col0 = n0 + wn * 64;
    if (EPI == 0) {
        #pragma unroll
        for (int mi = 0; mi < 2; ++mi)
            #pragma unroll
            for (int ni = 0; ni < 4; ++ni)
                #pragma unroll
                for (int r = 0; r < 4; ++r)
                    C[(size_t)(row0 + mi * 16 + g * 4 + r) * N + col0 + ni * 16 + li] = acc[mi][ni][r];
    } else {
        // fused RoPE + split. cols: [0,1024) q (pre-scaled), [1024,1280) k, [1280,1536) v.
        // rotate_half partner of col is col^32 == acc[mi][ni^2][r] (same wave, in-register).
        #pragma unroll
        for (int ni = 0; ni < 4; ++ni) {
            const int col = col0 + ni * 16 + li;
            const int d = col & 63;
            #pragma unroll
            for (int mi = 0; mi < 2; ++mi) {
                #pragma unroll
                for (int r = 0; r < 4; ++r) {
                    const int row = row0 + mi * 16 + g * 4 + r;
                    const int bb = row >> 11, s = row & 2047;
                    float val = acc[mi][ni][r];
                    if (col < 1280) {
                        const float pairv = acc[mi][ni ^ 2][r];
                        const float rot = (d < 32) ? -pairv : pairv;
                        val = val * cosp[s * 64 + d] + rot * sinp[s * 64 + d];
                    }
                    if (col < 1024) {
                        const int hh = col >> 6;
                        qo[(((size_t)bb * NH + hh) * SS + s) * HD + d] = (bf16)(val * SM_SCALE);
                    } else if (col < 1280) {
                        const int kh = (col - 1024) >> 6;
                        ko[(((size_t)bb * NKV + kh) * SS + s) * HD + d] = (bf16)val;
                    } else {
                        const int kh = (col - 1280) >> 6;
                        vto[(((size_t)bb * NKV + kh) * HD + d) * SS + s] = (bf16)val;  // V^T: [d][s]
                    }
                }
            }
        }
    }
}

// ---------------- Flash attention v6: LDS-staged, heavy-first LPT grid, 1 qt/block ----------------
// 1024 blocks x 256 thr. qt = 31 - blk/32 (heaviest first), (b,h) = blk&31.
// 45 KB LDS -> 3 blocks/CU co-resident; scheduler backfills short blocks (LPT).
#define FP 72
#define FPV 136
__global__ __launch_bounds__(256) void flash_kernel(const bf16* __restrict__ q, const bf16* __restrict__ k,
                                                    const bf16* __restrict__ vt, bf16* __restrict__ o)
{
    __shared__ bf16 Ks[128][FP];     // 128 keys x 64 d
    __shared__ bf16 Vt[64][FPV];     // 64 d x 128 keys
    __shared__ bf16 Ps[4][16][FP];   // per-wave P, column-XOR-swizzled by g

    const int blk = blockIdx.x;
    const int qt = 31 - (blk >> 5);          // heavy blocks dispatched first
    const int h = blk & 15;
    const int b = (blk >> 4) & 1;
    const int kvh = h >> 2;
    const int tid = threadIdx.x;
    const int w = tid >> 6, lane = tid & 63, g = lane >> 4, li = lane & 15;

    const bf16* qh = q + ((size_t)b * NH + h) * SS * HD;
    const bf16* kh = k + ((size_t)b * NKV + kvh) * SS * HD;
    const bf16* vh = vt + ((size_t)b * NKV + kvh) * (size_t)HD * SS;

    bf16x8 ones;
    #pragma unroll
    for (int j = 0; j < 8; ++j) ones[j] = (bf16)1.0f;
    const f32x4 z = {0.f, 0.f, 0.f, 0.f};

    // Q fragments straight from global (A-layout: row=li, k=g*8+j); Q pre-scaled.
    const bf16* qrow = qh + (size_t)(qt * 64 + w * 16 + li) * HD;
    bf16x8 qf[2];
    qf[0] = *(const bf16x8*)(qrow + g * 8);
    qf[1] = *(const bf16x8*)(qrow + 32 + g * 8);

    f32x4 o_acc[4], l_acc;
    #pragma unroll
    for (int nt = 0; nt < 4; ++nt) o_acc[nt] = z;
    l_acc = z;

    for (int kt0 = 0; kt0 <= qt; kt0 += 2) {
        __syncthreads();
        {   // stage 128 keys of K (rows=key, 2 thr/row x 32 elems) and V^T (rows=d, 4 thr/row x 32 elems)
            const int krow = tid >> 1, kcol = (tid & 1) * 32;
            const uint4* ks = (const uint4*)(kh + (size_t)(kt0 * 64 + krow) * HD + kcol);
            const uint4 a0 = ks[0], a1 = ks[1], a2 = ks[2], a3 = ks[3];
            *(uint4*)&Ks[krow][kcol]      = a0;
            *(uint4*)&Ks[krow][kcol + 8]  = a1;
            *(uint4*)&Ks[krow][kcol + 16] = a2;
            *(uint4*)&Ks[krow][kcol + 24] = a3;
            const int vrow = tid >> 2, vcol = (tid & 3) * 32;
            const uint4* vs = (const uint4*)(vh + (size_t)vrow * SS + kt0 * 64 + vcol);
            const uint4 c0 = vs[0], c1 = vs[1], c2 = vs[2], c3 = vs[3];
            *(uint4*)&Vt[vrow][vcol]      = c0;
            *(uint4*)&Vt[vrow][vcol + 8]  = c1;
            *(uint4*)&Vt[vrow][vcol + 16] = c2;
            *(uint4*)&Vt[vrow][vcol + 24] = c3;
        }
        __syncthreads();

        #pragma unroll
        for (int sub = 0; sub < 2; ++sub) {
            const int kt = kt0 + sub;
            if (kt > qt) break;

            // S = Q @ K^T  (16 q-rows x 64 keys per wave); scores arrive pre-scaled
            f32x4 s_acc[4];
            #pragma unroll
            for (int nt = 0; nt < 4; ++nt) s_acc[nt] = z;
            #pragma unroll
            for (int t = 0; t < 2; ++t)
                #pragma unroll
                for (int nt = 0; nt < 4; ++nt) {
                    const bf16x8 kf = *(const bf16x8*)&Ks[sub * 64 + nt * 16 + li][t * 32 + g * 8];
                    s_acc[nt] = __builtin_amdgcn_mfma_f32_16x16x32_bf16(qf[t], kf, s_acc[nt], 0, 0, 0);
                }

            // exp2 + P -> LDS (bf16), column swizzled by g. Diag tile masked separately.
            if (kt == qt) {
                const int qr0 = qt * 64 + w * 16 + g * 4;
                #pragma unroll
                for (int nt = 0; nt < 4; ++nt) {
                    const int key = kt * 64 + nt * 16 + li;
                    #pragma unroll
                    for (int r = 0; r < 4; ++r) {
                        float sv = s_acc[nt][r];
                        if (key > qr0 + r) sv = -1e30f;
                        Ps[w][g * 4 + r][(nt * 16 + li) ^ (g * 16)] = (bf16)exp2f(sv);
                    }
                }
            } else {
                #pragma unroll
                for (int nt = 0; nt < 4; ++nt)
                    #pragma unroll
                    for (int r = 0; r < 4; ++r)
                        Ps[w][g * 4 + r][(nt * 16 + li) ^ (g * 16)] = (bf16)exp2f(s_acc[nt][r]);
            }
            // same-wave LDS round-trip (C-layout -> A-layout); no barrier needed

            // O += P @ V ; l += P @ 1 (rowsum via ones-MFMA)
            #pragma unroll
            for (int t = 0; t < 2; ++t) {
                const bf16x8 pf = *(const bf16x8*)&Ps[w][li][(t * 32 + g * 8) ^ ((li >> 2) * 16)];
                l_acc = __builtin_amdgcn_mfma_f32_16x16x32_bf16(pf, ones, l_acc, 0, 0, 0);
                #pragma unroll
                for (int nt = 0; nt < 4; ++nt) {
                    const bf16x8 vf = *(const bf16x8*)&Vt[nt * 16 + li][sub * 64 + t * 32 + g * 8];
                    o_acc[nt] = __builtin_amdgcn_mfma_f32_16x16x32_bf16(pf, vf, o_acc[nt], 0, 0, 0);
                }
            }
        }
    }

    // epilogue: O / l -> (b, s, h, d) bf16
    #pragma unroll
    for (int r = 0; r < 4; ++r) {
        const float inv = 1.f / l_acc[r];
        const int s = qt * 64 + w * 16 + g * 4 + r;
        bf16* orow = o + (((size_t)b * SS + s) * NH + h) * HD;
        #pragma unroll
        for (int nt = 0; nt < 4; ++nt) orow[nt * 16 + li] = (bf16)(o_acc[nt][r] * inv);
    }
}

extern "C" void kernel_launch(void* const* d_in, const int* in_sizes, int n_in,
                              void* d_out, int out_size, void* d_ws, size_t ws_size,
                              hipStream_t stream) {
    const float* x     = (const float*)d_in[0];
    const float* cos_t = (const float*)d_in[1];
    const float* sin_t = (const float*)d_in[2];
    const float* Wq    = (const float*)d_in[3];
    const float* Wk    = (const float*)d_in[4];
    const float* Wv    = (const float*)d_in[5];
    const float* Wo    = (const float*)d_in[6];
    float* out = (float*)d_out;

    char* wsb = (char*)d_ws;
    bf16* x_b    = (bf16*)(wsb);                 //  8,388,608 B (aliased as o_b after QKV GEMM)
    bf16* wqkv_t = (bf16*)(wsb + 8388608);       //  3,145,728 B (1536 x 1024)
    bf16* wo_t   = (bf16*)(wsb + 11534336);      //  2,097,152 B (1024 x 1024)
    bf16* q_b    = (bf16*)(wsb + 13631488);      //  8,388,608 B
    bf16* k_b    = (bf16*)(wsb + 22020096);      //  2,097,152 B
    bf16* vt_b   = (bf16*)(wsb + 24117248);      //  2,097,152 B -> total 26,214,400 B
    bf16* o_b    = x_b;

    prep_kernel<<<1152, 256, 0, stream>>>(x, Wq, Wk, Wv, Wo, x_b, wqkv_t, wo_t);

    // QKV GEMM with fused RoPE + split (writes q_b pre-scaled, k_b, vt_b directly)
    gemm_bt_kernel<2><<<dim3(64, 12), 256, 0, stream>>>(x_b, wqkv_t, nullptr, cos_t, sin_t,
                                                        q_b, k_b, vt_b, 4096, 1536, 1024);
    flash_kernel<<<1024, 256, 0, stream>>>(q_b, k_b, vt_b, o_b);
    gemm_bt_kernel<0><<<dim3(64, 8), 256, 0, stream>>>(o_b, wo_t, out, nullptr, nullptr,
                                                       nullptr, nullptr, nullptr, 4096, 1024, 1024);
}

// Round 11
// 167.198 us; speedup vs baseline: 1.4659x; 1.0891x over previous
//
#include <hip/hip_runtime.h>

#define SS 2048
#define NH 16
#define NKV 4
#define HD 64

typedef __bf16 bf16;
typedef __bf16 bf16x8 __attribute__((ext_vector_type(8)));
typedef float f32x4 __attribute__((ext_vector_type(4)));

// softmax scale folded into Q at the QKV epilogue: (1/sqrt(64)) * log2(e)
#define SM_SCALE 0.18033688011f

__device__ __forceinline__ void gl_lds16(const bf16* g, bf16* l) {
    __builtin_amdgcn_global_load_lds((const __attribute__((address_space(1))) void*)g,
                                     (__attribute__((address_space(3))) void*)l, 16, 0, 0);
}

// ---------------- prep: transpose/convert weights only (x conversion fused into QKV GEMM) ----
// blocks 0..255: Wq (16x16 64-tiles), 256..319: Wk, 320..383: Wv, 384..639: Wo.
__global__ __launch_bounds__(256) void prep_kernel(
    const float* __restrict__ Wq, const float* __restrict__ Wk,
    const float* __restrict__ Wv, const float* __restrict__ Wo,
    bf16* __restrict__ wqkv_t, bf16* __restrict__ wo_t)
{
    const int blk = blockIdx.x;
    const int tid = threadIdx.x;
    const float* W; bf16* Wt; int N, n0, k0;
    if (blk < 256)      { W = Wq; Wt = wqkv_t;                       N = 1024; n0 = (blk & 15) * 64;         k0 = (blk >> 4) * 64; }
    else if (blk < 320) { W = Wk; Wt = wqkv_t + (size_t)1024 * 1024; N = 256;  n0 = ((blk - 256) & 3) * 64;  k0 = ((blk - 256) >> 2) * 64; }
    else if (blk < 384) { W = Wv; Wt = wqkv_t + (size_t)1280 * 1024; N = 256;  n0 = ((blk - 320) & 3) * 64;  k0 = ((blk - 320) >> 2) * 64; }
    else                { W = Wo; Wt = wo_t;                         N = 1024; n0 = ((blk - 384) & 15) * 64; k0 = ((blk - 384) >> 4) * 64; }

    __shared__ float Ts[64][65];
    const int c = tid & 63, rr = tid >> 6;
    #pragma unroll
    for (int i = 0; i < 16; ++i) {
        const int kk = i * 4 + rr;
        Ts[kk][c] = W[(size_t)(k0 + kk) * N + n0 + c];
    }
    __syncthreads();
    #pragma unroll
    for (int i = 0; i < 16; ++i) {
        const int nn = i * 4 + rr;
        Wt[(size_t)(n0 + nn) * 1024 + k0 + c] = (bf16)Ts[c][nn];
    }
}

// ---------------- bf16 MFMA GEMM, 256 threads (4 waves), 64x128 tile, BK=64 ----------------
// Bt(N,K) rm bf16 via global_load_lds. Wave grid 2x2: wave tile 32x64 -> 16 MFMA/wave/iter.
// Unpadded LDS with chunk-XOR swizzle: phys chunk p of row r holds logical chunk p^(r&7);
// frag reads use ((t*4+g)^(li&7)) -> 2-way conflicts only (free, m136).
// EPI=0: A bf16 (gl_lds), C fp32 plain.
// EPI=2: A fp32 (coalesced vector load + cvt + SWIZZLED ds_write), fused RoPE+QKV split, Q pre-scaled.
template<int EPI>
__global__ __launch_bounds__(256) void gemm_bt_kernel(
    const bf16* __restrict__ A, const float* __restrict__ Af,
    const bf16* __restrict__ Bt, float* __restrict__ C,
    const float* __restrict__ cosp, const float* __restrict__ sinp,
    bf16* __restrict__ qo, bf16* __restrict__ ko, bf16* __restrict__ vto,
    int M, int N, int K)
{
    __shared__ bf16 As[64 * 64];    //  8 KB
    __shared__ bf16 Bs[128 * 64];   // 16 KB
    const int m0 = blockIdx.x * 64, n0 = blockIdx.y * 128;
    const int tid = threadIdx.x;
    const int w = tid >> 6, lane = tid & 63, g = lane >> 4, li = lane & 15;
    const int wm = w >> 1, wn = w & 1;      // wave tile: rows wm*32+mi*16 (mi<2), cols wn*64+ni*16 (ni<4)

    f32x4 acc[2][4];
    const f32x4 z = {0.f, 0.f, 0.f, 0.f};
    #pragma unroll
    for (int i = 0; i < 2; ++i)
        #pragma unroll
        for (int j = 0; j < 4; ++j) acc[i][j] = z;

    // staging sweep = 256 thr x 16B = 32 rows x 64 elems; wave w covers rows w*8..w*8+7.
    const int srow = tid >> 3;                          // 0..31 (row within sweep)
    const int schunk = ((tid & 7) ^ (srow & 7)) * 8;    // swizzled 8-elem chunk (phys for ds_write, logical for gl_lds)
    const bf16* pB0 = Bt + (size_t)(n0 + srow) * K + schunk;
    const bf16* pB1 = Bt + (size_t)(n0 + 32 + srow) * K + schunk;
    const bf16* pB2 = Bt + (size_t)(n0 + 64 + srow) * K + schunk;
    const bf16* pB3 = Bt + (size_t)(n0 + 96 + srow) * K + schunk;
    bf16* lB0 = Bs + (size_t)w * 512;
    bf16* lB1 = Bs + 2048 + (size_t)w * 512;
    bf16* lB2 = Bs + 4096 + (size_t)w * 512;
    bf16* lB3 = Bs + 6144 + (size_t)w * 512;
    const bf16* pA0 = (EPI == 0) ? A + (size_t)(m0 + srow) * K + schunk : nullptr;
    const bf16* pA1 = (EPI == 0) ? A + (size_t)(m0 + 32 + srow) * K + schunk : nullptr;
    bf16* lA0 = As + (size_t)w * 512;
    bf16* lA1 = As + 2048 + (size_t)w * 512;

    for (int kk = 0; kk < K; kk += 64) {
        __syncthreads();
        if (EPI == 0) {
            gl_lds16(pA0 + kk, lA0);
            gl_lds16(pA1 + kk, lA1);
        } else {
            // A fp32 -> bf16 conversion fused into staging.
            // Load UNSWIZZLED lane chunk (tid&7) from global (coalesced), store at
            // SWIZZLED phys chunk schunk: phys p then holds logical p^(row&7). [r10 bug: both used schunk]
            #pragma unroll
            for (int s = 0; s < 2; ++s) {
                const float* src = Af + (size_t)(m0 + s * 32 + srow) * K + kk + (tid & 7) * 8;
                const float4 v0 = *(const float4*)src;
                const float4 v1 = *(const float4*)(src + 4);
                bf16x8 t8;
                t8[0] = (bf16)v0.x; t8[1] = (bf16)v0.y; t8[2] = (bf16)v0.z; t8[3] = (bf16)v0.w;
                t8[4] = (bf16)v1.x; t8[5] = (bf16)v1.y; t8[6] = (bf16)v1.z; t8[7] = (bf16)v1.w;
                *(bf16x8*)&As[(s * 32 + srow) * 64 + schunk] = t8;
            }
        }
        gl_lds16(pB0 + kk, lB0);
        gl_lds16(pB1 + kk, lB1);
        gl_lds16(pB2 + kk, lB2);
        gl_lds16(pB3 + kk, lB3);
        __syncthreads();
        #pragma unroll
        for (int t = 0; t < 2; ++t) {
            const int phys = ((t * 4 + g) ^ (li & 7)) * 8;
            bf16x8 af[2], bfr[4];
            #pragma unroll
            for (int mi = 0; mi < 2; ++mi) af[mi] = *(const bf16x8*)&As[(wm * 32 + mi * 16 + li) * 64 + phys];
            #pragma unroll
            for (int ni = 0; ni < 4; ++ni) bfr[ni] = *(const bf16x8*)&Bs[(wn * 64 + ni * 16 + li) * 64 + phys];
            #pragma unroll
            for (int mi = 0; mi < 2; ++mi)
                #pragma unroll
                for (int ni = 0; ni < 4; ++ni)
                    acc[mi][ni] = __builtin_amdgcn_mfma_f32_16x16x32_bf16(af[mi], bfr[ni], acc[mi][ni], 0, 0, 0);
        }
    }

    const int row0 = m0 + wm * 32, col0 = n0 + wn * 64;
    if (EPI == 0) {
        #pragma unroll
        for (int mi = 0; mi < 2; ++mi)
            #pragma unroll
            for (int ni = 0; ni < 4; ++ni)
                #pragma unroll
                for (int r = 0; r < 4; ++r)
                    C[(size_t)(row0 + mi * 16 + g * 4 + r) * N + col0 + ni * 16 + li] = acc[mi][ni][r];
    } else {
        // fused RoPE + split. cols: [0,1024) q (pre-scaled), [1024,1280) k, [1280,1536) v.
        // rotate_half partner of col is col^32 == acc[mi][ni^2][r] (same wave, in-register).
        #pragma unroll
        for (int ni = 0; ni < 4; ++ni) {
            const int col = col0 + ni * 16 + li;
            const int d = col & 63;
            #pragma unroll
            for (int mi = 0; mi < 2; ++mi) {
                #pragma unroll
                for (int r = 0; r < 4; ++r) {
                    const int row = row0 + mi * 16 + g * 4 + r;
                    const int bb = row >> 11, s = row & 2047;
                    float val = acc[mi][ni][r];
                    if (col < 1280) {
                        const float pairv = acc[mi][ni ^ 2][r];
                        const float rot = (d < 32) ? -pairv : pairv;
                        val = val * cosp[s * 64 + d] + rot * sinp[s * 64 + d];
                    }
                    if (col < 1024) {
                        const int hh = col >> 6;
                        qo[(((size_t)bb * NH + hh) * SS + s) * HD + d] = (bf16)(val * SM_SCALE);
                    } else if (col < 1280) {
                        const int kh = (col - 1024) >> 6;
                        ko[(((size_t)bb * NKV + kh) * SS + s) * HD + d] = (bf16)val;
                    } else {
                        const int kh = (col - 1280) >> 6;
                        vto[(((size_t)bb * NKV + kh) * HD + d) * SS + s] = (bf16)val;  // V^T: [d][s]
                    }
                }
            }
        }
    }
}

// ---------------- Flash attention v7: gl_lds-staged K/V, heavy-first LPT grid ----------------
// 1024 blocks x 256 thr. qt = 31 - blk/32 (heaviest first), (b,h) = blk&31.
// Ks/Vt unpadded + chunk-XOR swizzle, staged via global_load_lds (8 calls / 128 keys).
__global__ __launch_bounds__(256) void flash_kernel(const bf16* __restrict__ q, const bf16* __restrict__ k,
                                                    const bf16* __restrict__ vt, bf16* __restrict__ o)
{
    __shared__ bf16 Ks[128 * 64];    // 16 KB: 128 keys x 64 d, swizzled
    __shared__ bf16 Vt[64 * 128];    // 16 KB: 64 d x 128 keys, swizzled
    __shared__ bf16 Ps[4][16][72];   //  9 KB: per-wave P, column-XOR-swizzled by g

    const int blk = blockIdx.x;
    const int qt = 31 - (blk >> 5);          // heavy blocks dispatched first
    const int h = blk & 15;
    const int b = (blk >> 4) & 1;
    const int kvh = h >> 2;
    const int tid = threadIdx.x;
    const int w = tid >> 6, lane = tid & 63, g = lane >> 4, li = lane & 15;

    const bf16* qh = q + ((size_t)b * NH + h) * SS * HD;
    const bf16* kh = k + ((size_t)b * NKV + kvh) * SS * HD;
    const bf16* vh = vt + ((size_t)b * NKV + kvh) * (size_t)HD * SS;

    bf16x8 ones;
    #pragma unroll
    for (int j = 0; j < 8; ++j) ones[j] = (bf16)1.0f;
    const f32x4 z = {0.f, 0.f, 0.f, 0.f};

    // Q fragments straight from global (A-layout: row=li, k=g*8+j); Q pre-scaled.
    const bf16* qrow = qh + (size_t)(qt * 64 + w * 16 + li) * HD;
    bf16x8 qf[2];
    qf[0] = *(const bf16x8*)(qrow + g * 8);
    qf[1] = *(const bf16x8*)(qrow + 32 + g * 8);

    // staging lane maps (swizzled, wave-uniform LDS dests)
    const int ksrow = tid >> 3;                              // K: 0..31 within 32-row sweep
    const int kchunk = ((tid & 7) ^ (ksrow & 7)) * 8;
    const int vsrow = tid >> 4;                              // Vt: 0..15 within 16-row sweep
    const int vchunk = (((tid & 15) ^ (vsrow & 7)) & 15) * 8;
    bf16* lK = Ks + (size_t)w * 512;
    bf16* lV = Vt + (size_t)w * 512;

    f32x4 o_acc[4], l_acc;
    #pragma unroll
    for (int nt = 0; nt < 4; ++nt) o_acc[nt] = z;
    l_acc = z;

    for (int kt0 = 0; kt0 <= qt; kt0 += 2) {
        __syncthreads();
        {   // stage 128 keys of K (4 sweeps x 32 rows) and V^T (4 sweeps x 16 d-rows)
            #pragma unroll
            for (int s = 0; s < 4; ++s)
                gl_lds16(kh + (size_t)(kt0 * 64 + s * 32 + ksrow) * HD + kchunk, lK + s * 2048);
            #pragma unroll
            for (int s = 0; s < 4; ++s)
                gl_lds16(vh + (size_t)(s * 16 + vsrow) * SS + kt0 * 64 + vchunk, lV + s * 2048);
        }
        __syncthreads();

        #pragma unroll
        for (int sub = 0; sub < 2; ++sub) {
            const int kt = kt0 + sub;
            if (kt > qt) break;

            // S = Q @ K^T  (16 q-rows x 64 keys per wave); scores arrive pre-scaled
            f32x4 s_acc[4];
            #pragma unroll
            for (int nt = 0; nt < 4; ++nt) s_acc[nt] = z;
            #pragma unroll
            for (int t = 0; t < 2; ++t)
                #pragma unroll
                for (int nt = 0; nt < 4; ++nt) {
                    const bf16x8 kf = *(const bf16x8*)&Ks[(sub * 64 + nt * 16 + li) * 64 + (((t * 4 + g) ^ (li & 7)) * 8)];
                    s_acc[nt] = __builtin_amdgcn_mfma_f32_16x16x32_bf16(qf[t], kf, s_acc[nt], 0, 0, 0);
                }

            // exp2 + P -> LDS (bf16), column swizzled by g. Diag tile masked separately.
            if (kt == qt) {
                const int qr0 = qt * 64 + w * 16 + g * 4;
                #pragma unroll
                for (int nt = 0; nt < 4; ++nt) {
                    const int key = kt * 64 + nt * 16 + li;
                    #pragma unroll
                    for (int r = 0; r < 4; ++r) {
                        float sv = s_acc[nt][r];
                        if (key > qr0 + r) sv = -1e30f;
                        Ps[w][g * 4 + r][(nt * 16 + li) ^ (g * 16)] = (bf16)exp2f(sv);
                    }
                }
            } else {
                #pragma unroll
                for (int nt = 0; nt < 4; ++nt)
                    #pragma unroll
                    for (int r = 0; r < 4; ++r)
                        Ps[w][g * 4 + r][(nt * 16 + li) ^ (g * 16)] = (bf16)exp2f(s_acc[nt][r]);
            }
            // same-wave LDS round-trip (C-layout -> A-layout); no barrier needed

            // O += P @ V ; l += P @ 1 (rowsum via ones-MFMA)
            #pragma unroll
            for (int t = 0; t < 2; ++t) {
                const bf16x8 pf = *(const bf16x8*)&Ps[w][li][(t * 32 + g * 8) ^ ((li >> 2) * 16)];
                l_acc = __builtin_amdgcn_mfma_f32_16x16x32_bf16(pf, ones, l_acc, 0, 0, 0);
                #pragma unroll
                for (int nt = 0; nt < 4; ++nt) {
                    const bf16x8 vf = *(const bf16x8*)&Vt[(nt * 16 + li) * 128 + (((sub * 8 + t * 4 + g) ^ (li & 7)) * 8)];
                    o_acc[nt] = __builtin_amdgcn_mfma_f32_16x16x32_bf16(pf, vf, o_acc[nt], 0, 0, 0);
                }
            }
        }
    }

    // epilogue: O / l -> (b, s, h, d) bf16
    #pragma unroll
    for (int r = 0; r < 4; ++r) {
        const float inv = 1.f / l_acc[r];
        const int s = qt * 64 + w * 16 + g * 4 + r;
        bf16* orow = o + (((size_t)b * SS + s) * NH + h) * HD;
        #pragma unroll
        for (int nt = 0; nt < 4; ++nt) orow[nt * 16 + li] = (bf16)(o_acc[nt][r] * inv);
    }
}

extern "C" void kernel_launch(void* const* d_in, const int* in_sizes, int n_in,
                              void* d_out, int out_size, void* d_ws, size_t ws_size,
                              hipStream_t stream) {
    const float* x     = (const float*)d_in[0];
    const float* cos_t = (const float*)d_in[1];
    const float* sin_t = (const float*)d_in[2];
    const float* Wq    = (const float*)d_in[3];
    const float* Wk    = (const float*)d_in[4];
    const float* Wv    = (const float*)d_in[5];
    const float* Wo    = (const float*)d_in[6];
    float* out = (float*)d_out;

    char* wsb = (char*)d_ws;
    bf16* o_b    = (bf16*)(wsb);                 //  8,388,608 B (attention output)
    bf16* wqkv_t = (bf16*)(wsb + 8388608);       //  3,145,728 B (1536 x 1024)
    bf16* wo_t   = (bf16*)(wsb + 11534336);      //  2,097,152 B (1024 x 1024)
    bf16* q_b    = (bf16*)(wsb + 13631488);      //  8,388,608 B
    bf16* k_b    = (bf16*)(wsb + 22020096);      //  2,097,152 B
    bf16* vt_b   = (bf16*)(wsb + 24117248);      //  2,097,152 B -> total 26,214,400 B

    prep_kernel<<<640, 256, 0, stream>>>(Wq, Wk, Wv, Wo, wqkv_t, wo_t);

    // QKV GEMM: A = x (fp32, converted in-staging) with fused RoPE + split
    gemm_bt_kernel<2><<<dim3(64, 12), 256, 0, stream>>>(nullptr, x, wqkv_t, nullptr, cos_t, sin_t,
                                                        q_b, k_b, vt_b, 4096, 1536, 1024);
    flash_kernel<<<1024, 256, 0, stream>>>(q_b, k_b, vt_b, o_b);
    gemm_bt_kernel<0><<<dim3(64, 8), 256, 0, stream>>>(o_b, nullptr, wo_t, out, nullptr, nullptr,
                                                       nullptr, nullptr, nullptr, 4096, 1024, 1024);
}